// Round 1
// baseline (330.277 us; speedup 1.0000x reference)
//
#include <hip/hip_runtime.h>

#define BATCH 4096
#define IN_F 8192
#define OUT_F 8192
#define NG 1024
#define NW (NG * IN_F)
#define ROWS_PER_BLK 64

// K1: column partial sums of x (4096 x 8192, row-major), float4 vectorized.
// grid (8, 64): 8 column-groups of 1024 cols, 64 row-chunks of 64 rows.
__global__ __launch_bounds__(256) void colsum_kernel(const float* __restrict__ x,
                                                     float* __restrict__ colsum) {
    const int col4 = (blockIdx.x * 256 + threadIdx.x);            // float4 column index
    const int row0 = blockIdx.y * ROWS_PER_BLK;
    const float4* __restrict__ xp = (const float4*)x;
    const int stride4 = IN_F / 4;
    long long base = (long long)row0 * stride4 + col4;
    float a0 = 0.f, a1 = 0.f, a2 = 0.f, a3 = 0.f;
#pragma unroll 8
    for (int r = 0; r < ROWS_PER_BLK; ++r) {
        float4 v = xp[base + (long long)r * stride4];
        a0 += v.x; a1 += v.y; a2 += v.z; a3 += v.w;
    }
    float* dst = colsum + col4 * 4;
    atomicAdd(dst + 0, a0);
    atomicAdd(dst + 1, a1);
    atomicAdd(dst + 2, a2);
    atomicAdd(dst + 3, a3);
}

// K2: single block. val[j] = colsum[j]/BATCH; searchsorted(mins, val, 'right')-1
// via binary search on LDS copy of mins (exact semantics); gather weight; reduce s.
// Also detects out_mask storage layout (int32 vs 1-byte bool).
__global__ __launch_bounds__(256) void scalar_kernel(const float* __restrict__ colsum,
                                                     const float* __restrict__ mins,
                                                     const float* __restrict__ maxs,
                                                     const int* __restrict__ start_pos,
                                                     const int* __restrict__ offsets,
                                                     const int* __restrict__ sizes,
                                                     const float* __restrict__ wflat,
                                                     const unsigned char* __restrict__ mask_raw,
                                                     float* __restrict__ ws_scalars) {
    __shared__ float smins[NG];
    __shared__ float sred[256];
    __shared__ int sflag[256];
    const int t = threadIdx.x;
    for (int i = t; i < NG; i += 256) smins[i] = mins[i];

    // mask layout detection: read first 8192 bytes as 2048 int32.
    // int32 layout of 0/1 values -> every word is 0 or 1.
    // packed 1-byte bools (random half-ones) -> words like 0x01000101, not in {0,1}.
    const int* mi = (const int*)mask_raw;
    int ok = 1;
#pragma unroll
    for (int i = 0; i < 8; ++i) {
        int v = mi[t * 8 + i];
        ok &= (v == 0 || v == 1) ? 1 : 0;
    }
    sflag[t] = ok;
    __syncthreads();

    float local = 0.f;
    for (int j = t; j < IN_F; j += 256) {
        float val = colsum[j] * (1.0f / (float)BATCH);
        // searchsorted right: first index with mins[idx] > val
        int lo = 0, hi = NG;
        while (lo < hi) {
            int mid = (lo + hi) >> 1;
            if (smins[mid] <= val) lo = mid + 1; else hi = mid;
        }
        int g = lo - 1;
        if (g >= 0) {                       // g in [0, NG-1] here, so gc == g
            if (val >= smins[g] && val <= maxs[g]) {
                int pos = j - start_pos[g];
                if (pos >= 0 && pos < sizes[g]) {
                    long long idx = (long long)offsets[g] + (long long)pos;
                    if (idx < 0) idx = 0;
                    if (idx > (long long)(NW - 1)) idx = NW - 1;
                    local += val * wflat[idx];
                }
            }
        }
    }
    sred[t] = local;
    __syncthreads();
    for (int ofs = 128; ofs > 0; ofs >>= 1) {
        if (t < ofs) { sred[t] += sred[t + ofs]; sflag[t] &= sflag[t + ofs]; }
        __syncthreads();
    }
    if (t == 0) {
        ws_scalars[0] = sred[0];
        ((int*)ws_scalars)[1] = sflag[0];   // 1 => mask stored as int32
    }
}

// K3: write row 0 of the output (rest already zeroed by memset).
__global__ __launch_bounds__(256) void row0_kernel(const unsigned char* __restrict__ mask_raw,
                                                   const float* __restrict__ ws_scalars,
                                                   float* __restrict__ out) {
    const int j = blockIdx.x * 256 + threadIdx.x;
    if (j >= OUT_F) return;
    const float s = ws_scalars[0];
    const int mask_is_i32 = ((const int*)ws_scalars)[1];
    int m = mask_is_i32 ? ((const int*)mask_raw)[j] : (int)mask_raw[j];
    out[j] = m ? s : 0.0f;
}

extern "C" void kernel_launch(void* const* d_in, const int* in_sizes, int n_in,
                              void* d_out, int out_size, void* d_ws, size_t ws_size,
                              hipStream_t stream) {
    const float* x          = (const float*)d_in[0];
    const float* wflat      = (const float*)d_in[1];
    const float* mins       = (const float*)d_in[2];
    const float* maxs       = (const float*)d_in[3];
    const int*   start_pos  = (const int*)d_in[4];
    const int*   offsets    = (const int*)d_in[5];
    const int*   sizes      = (const int*)d_in[6];
    const unsigned char* mask = (const unsigned char*)d_in[7];
    float* out = (float*)d_out;

    float* colsum     = (float*)d_ws;          // IN_F floats
    float* ws_scalars = colsum + IN_F;         // [s, mask_is_i32]

    // ws/out are re-poisoned to 0xAA before every timed launch: zero what we use.
    hipMemsetAsync(colsum, 0, IN_F * sizeof(float), stream);
    hipMemsetAsync(d_out, 0, (size_t)out_size * sizeof(float), stream);

    colsum_kernel<<<dim3(IN_F / (256 * 4), BATCH / ROWS_PER_BLK), 256, 0, stream>>>(x, colsum);
    scalar_kernel<<<1, 256, 0, stream>>>(colsum, mins, maxs, start_pos, offsets, sizes,
                                         wflat, mask, ws_scalars);
    row0_kernel<<<OUT_F / 256, 256, 0, stream>>>(mask, ws_scalars, out);
}

// Round 2
// 328.270 us; speedup vs baseline: 1.0061x; 1.0061x over previous
//
#include <hip/hip_runtime.h>

#define BATCH 4096
#define IN_F 8192
#define OUT_F 8192
#define NG 1024
#define NW (NG * IN_F)
#define ROWS_PER_BLK 16   // 16 fully-unrolled float4 loads/thread -> high MLP

// K1: column partial sums of x (4096 x 8192, row-major), float4 vectorized.
// grid (8, 256): 8 column-groups of 1024 cols, 256 row-chunks of 16 rows.
// 2048 blocks = 8 blocks/CU; 16 independent loads in flight per thread.
__global__ __launch_bounds__(256) void colsum_kernel(const float* __restrict__ x,
                                                     float* __restrict__ colsum) {
    const int col4 = (blockIdx.x * 256 + threadIdx.x);            // float4 column index
    const int row0 = blockIdx.y * ROWS_PER_BLK;
    const float4* __restrict__ xp = (const float4*)x;
    const int stride4 = IN_F / 4;
    long long base = (long long)row0 * stride4 + col4;
    float4 v[ROWS_PER_BLK];
#pragma unroll
    for (int r = 0; r < ROWS_PER_BLK; ++r)
        v[r] = xp[base + (long long)r * stride4];
    float a0 = 0.f, a1 = 0.f, a2 = 0.f, a3 = 0.f;
#pragma unroll
    for (int r = 0; r < ROWS_PER_BLK; ++r) {
        a0 += v[r].x; a1 += v[r].y; a2 += v[r].z; a3 += v[r].w;
    }
    float* dst = colsum + col4 * 4;
    atomicAdd(dst + 0, a0);
    atomicAdd(dst + 1, a1);
    atomicAdd(dst + 2, a2);
    atomicAdd(dst + 3, a3);
}

// K2: single block. val[j] = colsum[j]/BATCH; searchsorted(mins, val, 'right')-1
// via binary search on LDS copy of mins (exact semantics); gather weight; reduce s.
// Also detects out_mask storage layout (int32 vs 1-byte bool).
__global__ __launch_bounds__(256) void scalar_kernel(const float* __restrict__ colsum,
                                                     const float* __restrict__ mins,
                                                     const float* __restrict__ maxs,
                                                     const int* __restrict__ start_pos,
                                                     const int* __restrict__ offsets,
                                                     const int* __restrict__ sizes,
                                                     const float* __restrict__ wflat,
                                                     const unsigned char* __restrict__ mask_raw,
                                                     float* __restrict__ ws_scalars) {
    __shared__ float smins[NG];
    __shared__ float sred[256];
    __shared__ int sflag[256];
    const int t = threadIdx.x;
    for (int i = t; i < NG; i += 256) smins[i] = mins[i];

    // mask layout detection: read first 8192 bytes as 2048 int32.
    // int32 layout of 0/1 values -> every word is 0 or 1.
    // packed 1-byte bools (random half-ones) -> words like 0x01000101, not in {0,1}.
    const int* mi = (const int*)mask_raw;
    int ok = 1;
#pragma unroll
    for (int i = 0; i < 8; ++i) {
        int v = mi[t * 8 + i];
        ok &= (v == 0 || v == 1) ? 1 : 0;
    }
    sflag[t] = ok;
    __syncthreads();

    float local = 0.f;
    for (int j = t; j < IN_F; j += 256) {
        float val = colsum[j] * (1.0f / (float)BATCH);
        // searchsorted right: first index with mins[idx] > val
        int lo = 0, hi = NG;
        while (lo < hi) {
            int mid = (lo + hi) >> 1;
            if (smins[mid] <= val) lo = mid + 1; else hi = mid;
        }
        int g = lo - 1;
        if (g >= 0) {                       // g in [0, NG-1] here, so gc == g
            if (val >= smins[g] && val <= maxs[g]) {
                int pos = j - start_pos[g];
                if (pos >= 0 && pos < sizes[g]) {
                    long long idx = (long long)offsets[g] + (long long)pos;
                    if (idx < 0) idx = 0;
                    if (idx > (long long)(NW - 1)) idx = NW - 1;
                    local += val * wflat[idx];
                }
            }
        }
    }
    sred[t] = local;
    __syncthreads();
    for (int ofs = 128; ofs > 0; ofs >>= 1) {
        if (t < ofs) { sred[t] += sred[t + ofs]; sflag[t] &= sflag[t + ofs]; }
        __syncthreads();
    }
    if (t == 0) {
        ws_scalars[0] = sred[0];
        ((int*)ws_scalars)[1] = sflag[0];   // 1 => mask stored as int32
    }
}

// K3: write row 0 of the output (rest already zeroed by memset).
__global__ __launch_bounds__(256) void row0_kernel(const unsigned char* __restrict__ mask_raw,
                                                   const float* __restrict__ ws_scalars,
                                                   float* __restrict__ out) {
    const int j = blockIdx.x * 256 + threadIdx.x;
    if (j >= OUT_F) return;
    const float s = ws_scalars[0];
    const int mask_is_i32 = ((const int*)ws_scalars)[1];
    int m = mask_is_i32 ? ((const int*)mask_raw)[j] : (int)mask_raw[j];
    out[j] = m ? s : 0.0f;
}

extern "C" void kernel_launch(void* const* d_in, const int* in_sizes, int n_in,
                              void* d_out, int out_size, void* d_ws, size_t ws_size,
                              hipStream_t stream) {
    const float* x          = (const float*)d_in[0];
    const float* wflat      = (const float*)d_in[1];
    const float* mins       = (const float*)d_in[2];
    const float* maxs       = (const float*)d_in[3];
    const int*   start_pos  = (const int*)d_in[4];
    const int*   offsets    = (const int*)d_in[5];
    const int*   sizes      = (const int*)d_in[6];
    const unsigned char* mask = (const unsigned char*)d_in[7];
    float* out = (float*)d_out;

    float* colsum     = (float*)d_ws;          // IN_F floats
    float* ws_scalars = colsum + IN_F;         // [s, mask_is_i32]

    // ws/out are re-poisoned to 0xAA before every timed launch: zero what we use.
    hipMemsetAsync(colsum, 0, IN_F * sizeof(float), stream);
    hipMemsetAsync(d_out, 0, (size_t)out_size * sizeof(float), stream);

    colsum_kernel<<<dim3(IN_F / (256 * 4), BATCH / ROWS_PER_BLK), 256, 0, stream>>>(x, colsum);
    scalar_kernel<<<1, 256, 0, stream>>>(colsum, mins, maxs, start_pos, offsets, sizes,
                                         wflat, mask, ws_scalars);
    row0_kernel<<<OUT_F / 256, 256, 0, stream>>>(mask, ws_scalars, out);
}

// Round 3
// 275.526 us; speedup vs baseline: 1.1987x; 1.1914x over previous
//
#include <hip/hip_runtime.h>

#define BATCH 4096
#define IN_F 8192
#define OUT_F 8192
#define NG 1024
#define NW (NG * IN_F)
#define ROWS_PER_BLK 16   // 16 fully-unrolled float4 loads/thread -> high MLP

// K1: column partial sums of x (4096 x 8192, row-major), float4 vectorized.
// grid (8, 256): 2048 blocks = 8 blocks/CU; 16 independent loads in flight/thread.
__global__ __launch_bounds__(256) void colsum_kernel(const float* __restrict__ x,
                                                     float* __restrict__ colsum) {
    const int col4 = (blockIdx.x * 256 + threadIdx.x);            // float4 column index
    const int row0 = blockIdx.y * ROWS_PER_BLK;
    const float4* __restrict__ xp = (const float4*)x;
    const int stride4 = IN_F / 4;
    long long base = (long long)row0 * stride4 + col4;
    float4 v[ROWS_PER_BLK];
#pragma unroll
    for (int r = 0; r < ROWS_PER_BLK; ++r)
        v[r] = xp[base + (long long)r * stride4];
    float a0 = 0.f, a1 = 0.f, a2 = 0.f, a3 = 0.f;
#pragma unroll
    for (int r = 0; r < ROWS_PER_BLK; ++r) {
        a0 += v[r].x; a1 += v[r].y; a2 += v[r].z; a3 += v[r].w;
    }
    float* dst = colsum + col4 * 4;
    atomicAdd(dst + 0, a0);
    atomicAdd(dst + 1, a1);
    atomicAdd(dst + 2, a2);
    atomicAdd(dst + 3, a3);
}

// K2 (parallelized): 32 blocks x 256 threads, one column each. All group tables
// (mins/start_pos/offsets/sizes) staged in LDS so the only dependent global
// load is wflat[idx]. Partial sums atomicAdd'ed into ws_scalars[0].
// Block 0 additionally detects the out_mask storage layout (int32 vs 1-byte).
__global__ __launch_bounds__(256) void scalar_kernel(const float* __restrict__ colsum,
                                                     const float* __restrict__ mins,
                                                     const float* __restrict__ maxs,
                                                     const int* __restrict__ start_pos,
                                                     const int* __restrict__ offsets,
                                                     const int* __restrict__ sizes,
                                                     const float* __restrict__ wflat,
                                                     const unsigned char* __restrict__ mask_raw,
                                                     float* __restrict__ ws_scalars) {
    __shared__ float smins[NG];
    __shared__ int sstart[NG];
    __shared__ int soffs[NG];
    __shared__ int ssize[NG];
    __shared__ float sred[256];
    const int t = threadIdx.x;
    for (int i = t; i < NG; i += 256) {
        smins[i]  = mins[i];
        sstart[i] = start_pos[i];
        soffs[i]  = offsets[i];
        ssize[i]  = sizes[i];
    }
    __syncthreads();

    const int j = blockIdx.x * 256 + t;       // 32*256 == IN_F exactly
    float val = colsum[j] * (1.0f / (float)BATCH);
    // searchsorted right: first index with mins[idx] > val
    int lo = 0, hi = NG;
    while (lo < hi) {
        int mid = (lo + hi) >> 1;
        if (smins[mid] <= val) lo = mid + 1; else hi = mid;
    }
    int g = lo - 1;
    float local = 0.f;
    if (g >= 0 && val >= smins[g] && val <= maxs[g]) {
        int pos = j - sstart[g];
        if (pos >= 0 && pos < ssize[g]) {
            long long idx = (long long)soffs[g] + (long long)pos;
            if (idx < 0) idx = 0;
            if (idx > (long long)(NW - 1)) idx = NW - 1;
            local = val * wflat[idx];
        }
    }
    sred[t] = local;
    __syncthreads();
    for (int ofs = 128; ofs > 0; ofs >>= 1) {
        if (t < ofs) sred[t] += sred[t + ofs];
        __syncthreads();
    }
    if (t == 0) atomicAdd(&ws_scalars[0], sred[0]);

    // mask layout detection (block 0 only): first 8192 bytes as 2048 int32.
    // int32 0/1 layout -> every word in {0,1}; packed bools -> words like 0x01000101.
    if (blockIdx.x == 0) {
        const int* mi = (const int*)mask_raw;
        int ok = 1;
#pragma unroll
        for (int i = 0; i < 8; ++i) {
            int v = mi[t * 8 + i];
            ok &= (v == 0 || v == 1) ? 1 : 0;
        }
        __syncthreads();
        ((unsigned long long)0);
        __shared__ int sflag[256];
        sflag[t] = ok;
        __syncthreads();
        for (int ofs = 128; ofs > 0; ofs >>= 1) {
            if (t < ofs) sflag[t] &= sflag[t + ofs];
            __syncthreads();
        }
        if (t == 0) ((int*)ws_scalars)[1] = sflag[0];   // 1 => int32 layout
    }
}

// K3: write the entire output: zeros everywhere, row 0 = mask ? s : 0.
// Grid-stride float4 stores; 2048 blocks x 256 threads, 16 float4 per thread.
__global__ __launch_bounds__(256) void out_kernel(const unsigned char* __restrict__ mask_raw,
                                                  const float* __restrict__ ws_scalars,
                                                  float4* __restrict__ out4) {
    const long long total4 = (long long)BATCH * OUT_F / 4;
    const long long stride = (long long)gridDim.x * blockDim.x;
    long long i = (long long)blockIdx.x * blockDim.x + threadIdx.x;
    const float s = ws_scalars[0];
    const int mask_is_i32 = ((const int*)ws_scalars)[1];
    for (; i < total4; i += stride) {
        float4 v = make_float4(0.f, 0.f, 0.f, 0.f);
        if (i < OUT_F / 4) {                 // row 0
            const int j = (int)i * 4;
            int m0, m1, m2, m3;
            if (mask_is_i32) {
                const int* mi = (const int*)mask_raw;
                m0 = mi[j]; m1 = mi[j + 1]; m2 = mi[j + 2]; m3 = mi[j + 3];
            } else {
                m0 = mask_raw[j]; m1 = mask_raw[j + 1];
                m2 = mask_raw[j + 2]; m3 = mask_raw[j + 3];
            }
            v.x = m0 ? s : 0.f; v.y = m1 ? s : 0.f;
            v.z = m2 ? s : 0.f; v.w = m3 ? s : 0.f;
        }
        out4[i] = v;
    }
}

extern "C" void kernel_launch(void* const* d_in, const int* in_sizes, int n_in,
                              void* d_out, int out_size, void* d_ws, size_t ws_size,
                              hipStream_t stream) {
    const float* x          = (const float*)d_in[0];
    const float* wflat      = (const float*)d_in[1];
    const float* mins       = (const float*)d_in[2];
    const float* maxs       = (const float*)d_in[3];
    const int*   start_pos  = (const int*)d_in[4];
    const int*   offsets    = (const int*)d_in[5];
    const int*   sizes      = (const int*)d_in[6];
    const unsigned char* mask = (const unsigned char*)d_in[7];

    float* colsum     = (float*)d_ws;          // IN_F floats
    float* ws_scalars = colsum + IN_F;         // [s (atomic), mask_is_i32]

    // ws is re-poisoned to 0xAA before every timed launch: zero what we use
    // (colsum accumulators + the s/flag scalars).
    hipMemsetAsync(colsum, 0, IN_F * sizeof(float) + 8, stream);

    colsum_kernel<<<dim3(IN_F / (256 * 4), BATCH / ROWS_PER_BLK), 256, 0, stream>>>(x, colsum);
    scalar_kernel<<<IN_F / 256, 256, 0, stream>>>(colsum, mins, maxs, start_pos, offsets,
                                                  sizes, wflat, mask, ws_scalars);
    out_kernel<<<2048, 256, 0, stream>>>(mask, ws_scalars, (float4*)d_out);
}

// Round 4
// 274.781 us; speedup vs baseline: 1.2020x; 1.0027x over previous
//
#include <hip/hip_runtime.h>

#define BATCH 4096
#define IN_F 8192
#define OUT_F 8192
#define NG 1024
#define NW (NG * IN_F)
#define RCHUNKS 256        // row chunks of 16 rows each
#define ROWS_PER_BLK 16    // 16 fully-unrolled float4 loads/thread -> high MLP

// ws layout (floats): part[RCHUNKS * IN_F] (8 MB) | spart[32] | flag(int)
// No memset needed: every word we read is plain-stored by an earlier kernel.

// K1: per-rowchunk column partial sums of x (4096 x 8192 row-major).
// grid (8, 256): 2048 blocks; plain float4 stores, no atomics.
__global__ __launch_bounds__(256) void colsum_kernel(const float* __restrict__ x,
                                                     float4* __restrict__ part4) {
    const int col4 = blockIdx.x * 256 + threadIdx.x;              // 0..2047
    const int y = blockIdx.y;                                     // row chunk
    const float4* __restrict__ xp = (const float4*)x;
    const int stride4 = IN_F / 4;
    long long base = (long long)(y * ROWS_PER_BLK) * stride4 + col4;
    float4 v[ROWS_PER_BLK];
#pragma unroll
    for (int r = 0; r < ROWS_PER_BLK; ++r)
        v[r] = xp[base + (long long)r * stride4];
    float a0 = 0.f, a1 = 0.f, a2 = 0.f, a3 = 0.f;
#pragma unroll
    for (int r = 0; r < ROWS_PER_BLK; ++r) {
        a0 += v[r].x; a1 += v[r].y; a2 += v[r].z; a3 += v[r].w;
    }
    part4[(long long)y * stride4 + col4] = make_float4(a0, a1, a2, a3);
}

// K2: 32 blocks x 256 threads, one column each. Reduce the 256 partials per
// column, then searchsorted(mins,val,'right')-1 on LDS tables, gather weight,
// block-reduce, plain-store spart[block]. Block 0 also detects the out_mask
// storage layout (int32 vs 1-byte bool) and plain-stores the flag.
__global__ __launch_bounds__(256) void scalar_kernel(const float* __restrict__ part,
                                                     const float* __restrict__ mins,
                                                     const float* __restrict__ maxs,
                                                     const int* __restrict__ start_pos,
                                                     const int* __restrict__ offsets,
                                                     const int* __restrict__ sizes,
                                                     const float* __restrict__ wflat,
                                                     const unsigned char* __restrict__ mask_raw,
                                                     float* __restrict__ spart,
                                                     int* __restrict__ flag) {
    __shared__ float smins[NG];
    __shared__ int sstart[NG];
    __shared__ int soffs[NG];
    __shared__ int ssize[NG];
    __shared__ float sred[256];
    const int t = threadIdx.x;
    for (int i = t; i < NG; i += 256) {
        smins[i]  = mins[i];
        sstart[i] = start_pos[i];
        soffs[i]  = offsets[i];
        ssize[i]  = sizes[i];
    }
    __syncthreads();

    const int j = blockIdx.x * 256 + t;       // 32*256 == IN_F exactly
    float csum = 0.f;
#pragma unroll 8
    for (int y = 0; y < RCHUNKS; ++y)
        csum += part[(long long)y * IN_F + j];
    float val = csum * (1.0f / (float)BATCH);

    // searchsorted right: first index with mins[idx] > val
    int lo = 0, hi = NG;
    while (lo < hi) {
        int mid = (lo + hi) >> 1;
        if (smins[mid] <= val) lo = mid + 1; else hi = mid;
    }
    int g = lo - 1;
    float local = 0.f;
    if (g >= 0 && val >= smins[g] && val <= maxs[g]) {
        int pos = j - sstart[g];
        if (pos >= 0 && pos < ssize[g]) {
            long long idx = (long long)soffs[g] + (long long)pos;
            if (idx < 0) idx = 0;
            if (idx > (long long)(NW - 1)) idx = NW - 1;
            local = val * wflat[idx];
        }
    }
    sred[t] = local;
    __syncthreads();
    for (int ofs = 128; ofs > 0; ofs >>= 1) {
        if (t < ofs) sred[t] += sred[t + ofs];
        __syncthreads();
    }
    if (t == 0) spart[blockIdx.x] = sred[0];

    // mask layout detection (block 0): first 8192 bytes as 2048 int32.
    // int32 0/1 layout -> every word in {0,1}; packed bools -> words like 0x01000101.
    if (blockIdx.x == 0) {
        const int* mi = (const int*)mask_raw;
        int ok = 1;
#pragma unroll
        for (int i = 0; i < 8; ++i) {
            int v = mi[t * 8 + i];
            ok &= (v == 0 || v == 1) ? 1 : 0;
        }
        __shared__ int sflag[256];
        sflag[t] = ok;
        __syncthreads();
        for (int ofs = 128; ofs > 0; ofs >>= 1) {
            if (t < ofs) sflag[t] &= sflag[t + ofs];
            __syncthreads();
        }
        if (t == 0) *flag = sflag[0];         // 1 => int32 layout
    }
}

// K3: write the entire output: zeros everywhere, row 0 = mask ? s : 0.
// Row-0 threads reconstruct s from the 32 block partials (L2-broadcast reads).
__global__ __launch_bounds__(256) void out_kernel(const unsigned char* __restrict__ mask_raw,
                                                  const float* __restrict__ spart,
                                                  const int* __restrict__ flag,
                                                  float4* __restrict__ out4) {
    const long long total4 = (long long)BATCH * OUT_F / 4;
    const long long stride = (long long)gridDim.x * blockDim.x;
    long long i = (long long)blockIdx.x * blockDim.x + threadIdx.x;
    for (; i < total4; i += stride) {
        float4 v = make_float4(0.f, 0.f, 0.f, 0.f);
        if (i < OUT_F / 4) {                 // row 0
            const float4* sp4 = (const float4*)spart;
            float4 p0 = sp4[0], p1 = sp4[1], p2 = sp4[2], p3 = sp4[3];
            float4 p4 = sp4[4], p5 = sp4[5], p6 = sp4[6], p7 = sp4[7];
            float s = ((p0.x + p0.y + p0.z + p0.w) + (p1.x + p1.y + p1.z + p1.w))
                    + ((p2.x + p2.y + p2.z + p2.w) + (p3.x + p3.y + p3.z + p3.w))
                    + ((p4.x + p4.y + p4.z + p4.w) + (p5.x + p5.y + p5.z + p5.w))
                    + ((p6.x + p6.y + p6.z + p6.w) + (p7.x + p7.y + p7.z + p7.w));
            const int mask_is_i32 = *flag;
            const int j = (int)i * 4;
            int m0, m1, m2, m3;
            if (mask_is_i32) {
                const int* mi = (const int*)mask_raw;
                m0 = mi[j]; m1 = mi[j + 1]; m2 = mi[j + 2]; m3 = mi[j + 3];
            } else {
                m0 = mask_raw[j]; m1 = mask_raw[j + 1];
                m2 = mask_raw[j + 2]; m3 = mask_raw[j + 3];
            }
            v.x = m0 ? s : 0.f; v.y = m1 ? s : 0.f;
            v.z = m2 ? s : 0.f; v.w = m3 ? s : 0.f;
        }
        out4[i] = v;
    }
}

extern "C" void kernel_launch(void* const* d_in, const int* in_sizes, int n_in,
                              void* d_out, int out_size, void* d_ws, size_t ws_size,
                              hipStream_t stream) {
    const float* x          = (const float*)d_in[0];
    const float* wflat      = (const float*)d_in[1];
    const float* mins       = (const float*)d_in[2];
    const float* maxs       = (const float*)d_in[3];
    const int*   start_pos  = (const int*)d_in[4];
    const int*   offsets    = (const int*)d_in[5];
    const int*   sizes      = (const int*)d_in[6];
    const unsigned char* mask = (const unsigned char*)d_in[7];

    float* part   = (float*)d_ws;                       // RCHUNKS*IN_F floats (8 MB)
    float* spart  = part + (long long)RCHUNKS * IN_F;   // 32 floats
    int*   flag   = (int*)(spart + 32);                 // 1 int

    colsum_kernel<<<dim3(IN_F / (256 * 4), RCHUNKS), 256, 0, stream>>>(x, (float4*)part);
    scalar_kernel<<<IN_F / 256, 256, 0, stream>>>(part, mins, maxs, start_pos, offsets,
                                                  sizes, wflat, mask, spart, flag);
    out_kernel<<<2048, 256, 0, stream>>>(mask, spart, flag, (float4*)d_out);
}